// Round 4
// baseline (208.912 us; speedup 1.0000x reference)
//
#include <hip/hip_runtime.h>
#include <hip/hip_bf16.h>
#include <stdint.h>

#define T_STEPS 64
#define B_SZ 8
#define C_DIM 64
#define V_SZ 16000
#define K_DIM 4096   // C*C
#define M_ROWS 512   // T*B
#define BN 64
#define BM 256              // M-split 2
#define BK 32
#define NITER (K_DIM / BK)  // 128
#define ATILE_BYTES 32768   // 512 rows * 32 k * 2B, blocked [g][row512][16B]
#define NWG 500             // (M_ROWS/BM) * (V_SZ/BN)

typedef __bf16 bf16x8 __attribute__((ext_vector_type(8)));
typedef float f32x4 __attribute__((ext_vector_type(4)));

// ---------------- Kernel 1: sequential ctx recurrence ----------------
__global__ void ctx_kernel(const int* __restrict__ tokens,
                           const float* __restrict__ emb_ctx,
                           const float* __restrict__ beta_mult,
                           const float* __restrict__ beta_power,
                           float* __restrict__ ctx_hist) {
  const int b = blockIdx.x;
  const int d = threadIdx.x;
  const float bm = beta_mult[0];
  const float bp = beta_power[0];
  float ctx = 0.0f;
  for (int t = 0; t < T_STEPS; ++t) {
    const int tok = tokens[t * B_SZ + b];
    const float ce = emb_ctx[tok * C_DIM + d];
    float ne2 = ce * ce;
    float c2 = ctx * ctx;
#pragma unroll
    for (int s = 32; s > 0; s >>= 1) {
      ne2 += __shfl_xor(ne2, s, 64);
      c2 += __shfl_xor(c2, s, 64);
    }
    const float ne = sqrtf(ne2);
    const float nc = sqrtf(c2);
    float beta = powf(bm * (ne / (ne + nc)), bp);  // ALPHA == 1
    beta = fminf(fmaxf(beta, 0.0f), 1.0f);
    ctx = (1.0f - beta) * ctx + beta * ce;
    ctx_hist[(t * B_SZ + b) * C_DIM + d] = ctx;
  }
}

// ---------------- Kernel 2: build M in MFMA-fragment-blocked layout ----------
// Element (row m, k) -> byte (k>>5)*32768 + ((k>>3)&3)*8192 + m*16 + (k&7)*2.
__global__ void build_m(const int* __restrict__ tokens,
                        const float* __restrict__ emb_act,
                        const float* __restrict__ ctx_hist,
                        char* __restrict__ Mblk) {
  const int m = blockIdx.x;
  const int tid = threadIdx.x;
  __shared__ float ctxs[C_DIM];
  __shared__ float aes[C_DIM];
  const int t = m >> 3, b = m & 7;
  const int tok = tokens[t * B_SZ + b];
  if (tid < C_DIM) {
    ctxs[tid] = ctx_hist[m * C_DIM + tid];
    aes[tid] = emb_act[tok * C_DIM + tid];
  }
  __syncthreads();
  const int c = tid >> 1;
  const int dh = (tid & 1) * 32;
  const float ae = aes[c];
#pragma unroll
  for (int q = 0; q < 4; ++q) {
    const int k0 = c * C_DIM + dh + q * 8;
    bf16x8 v;
#pragma unroll
    for (int jj = 0; jj < 8; ++jj) v[jj] = (__bf16)(ae * ctxs[dh + q * 8 + jj]);
    *(bf16x8*)(void*)(Mblk + (size_t)(k0 >> 5) * 32768 + ((k0 >> 3) & 3) * 8192 +
                      m * 16) = v;
  }
}

// ---------------- Kernel 3: GEMM out[512,16000] = M[512,4096] * W^T ------------
// Grid 500 = 2 M-blocks x 250 N-panels -> ~2 blocks/CU (the R3 fix: a second
// independent block fills each barrier stall). Bijective XCD swizzle puts the
// 2 blocks sharing a W panel on the same XCD (W L2-shared, read once from HBM).
// A: global->VGPR frags (blocked Mblk, L2-resident; W loads are nontemporal so
// they don't evict it). W: f32x4 nt-loads depth-3 reg ring -> cvt bf16 ->
// 4-slot LDS. One counted barrier per iter, no vmcnt(0) in the loop.
__global__ __launch_bounds__(256, 2)
void gemm_kernel(const char* __restrict__ Ablk, const float* __restrict__ W,
                 float* __restrict__ out) {
  __shared__ char wlds[4][4096];  // [slot][g][col64][16B] bf16
  const int tid = threadIdx.x;
  const int lane = tid & 63;
  const int w = tid >> 6;
  const int lrow = lane & 15;
  const int g = lane >> 4;

  // m204 bijective XCD swizzle: NWG=500, q=62, r=4. Blocks orig%8==x land on
  // XCD x; give each XCD a contiguous logical range so wg pairs (2nj,2nj+1)
  // share an XCD.
  const int orig = blockIdx.x;
  const int xcd = orig & 7;
  const int wg = ((xcd < 4) ? xcd * 63 : 4 * 63 + (xcd - 4) * 62) + (orig >> 3);
  const int mi = wg & 1;
  const int n0 = (wg >> 1) * BN;
  const int m0 = mi * BM;

  // A-fragment per-lane byte offsets within a 32KB tile
  int aoff[4];
#pragma unroll
  for (int fm = 0; fm < 4; ++fm)
    aoff[fm] = g * 8192 + (m0 + w * 64 + fm * 16 + lrow) * 16;

  // W staging: thread t loads 8 consecutive f32 (2 x f32x4) of row n0+(t>>2),
  // k-chunk (t&3)*8. Per wave: 16 rows x 128B contiguous -> fully coalesced.
  const char* const Wc = (const char*)W;
  const size_t wvoff = ((size_t)(n0 + (tid >> 2)) * K_DIM + (tid & 3) * 8) * 4;
  // LDS: slot + g*1024 + col*16, g=t&3, col=t>>2
  const int wldsoff = (tid & 3) * 1024 + (tid >> 2) * 16;

  f32x4 acc[4][4];
#pragma unroll
  for (int fm = 0; fm < 4; ++fm)
#pragma unroll
    for (int fn = 0; fn < 4; ++fn) acc[fm][fn] = (f32x4){0.f, 0.f, 0.f, 0.f};

  bf16x8 a2[2][4];
  f32x4 wr[4][2];

  // ---- prologue: W(0),W(1),A(0),W(2); write W-tile 0 to slot 0 ----
  wr[0][0] = __builtin_nontemporal_load((const f32x4*)(Wc + wvoff));
  wr[0][1] = __builtin_nontemporal_load((const f32x4*)(Wc + wvoff + 16));
  wr[1][0] = __builtin_nontemporal_load((const f32x4*)(Wc + wvoff + 128));
  wr[1][1] = __builtin_nontemporal_load((const f32x4*)(Wc + wvoff + 144));
#pragma unroll
  for (int fm = 0; fm < 4; ++fm) a2[0][fm] = *(const bf16x8*)(Ablk + aoff[fm]);
  wr[2][0] = __builtin_nontemporal_load((const f32x4*)(Wc + wvoff + 256));
  wr[2][1] = __builtin_nontemporal_load((const f32x4*)(Wc + wvoff + 272));
  {
    bf16x8 h;
#pragma unroll
    for (int q = 0; q < 4; ++q) { h[q] = (__bf16)wr[0][0][q]; h[4 + q] = (__bf16)wr[0][1][q]; }
    *(bf16x8*)(wlds[0] + wldsoff) = h;
  }
  asm volatile("s_waitcnt lgkmcnt(0)" ::: "memory");
  __builtin_amdgcn_s_barrier();
  __builtin_amdgcn_sched_barrier(0);

#pragma unroll 1
  for (int bb = 0; bb < NITER / 4; ++bb) {
#pragma unroll
    for (int j = 0; j < 4; ++j) {
      const int kt = bb * 4 + j;
      // 1. issue A(kt+1) -> a2[(j+1)&1]   (clamped on last iter)
      const int kta = (kt + 1 < NITER) ? kt + 1 : kt;
      const char* ap = Ablk + (size_t)kta * ATILE_BYTES;
#pragma unroll
      for (int fm = 0; fm < 4; ++fm)
        a2[(j + 1) & 1][fm] = *(const bf16x8*)(ap + aoff[fm]);
      // 2. issue W(kt+3) -> wr[(j+3)&3]
      const int ktw = (kt + 3 < NITER) ? kt + 3 : NITER - 1;
      wr[(j + 3) & 3][0] =
          __builtin_nontemporal_load((const f32x4*)(Wc + wvoff + (size_t)ktw * 128));
      wr[(j + 3) & 3][1] =
          __builtin_nontemporal_load((const f32x4*)(Wc + wvoff + (size_t)ktw * 128 + 16));
      // 3. cvt + ds_write W(kt+1) into slot (j+1)&3
      {
        bf16x8 h;
#pragma unroll
        for (int q = 0; q < 4; ++q) {
          h[q] = (__bf16)wr[(j + 1) & 3][0][q];
          h[4 + q] = (__bf16)wr[(j + 1) & 3][1][q];
        }
        *(bf16x8*)(wlds[(j + 1) & 3] + wldsoff) = h;
      }
      // 4. one barrier per iter; vmem prefetches stay in flight
      asm volatile("s_waitcnt lgkmcnt(0)" ::: "memory");
      __builtin_amdgcn_s_barrier();
      __builtin_amdgcn_sched_barrier(0);
      // 5. compute kt from wlds[j&3] + a2[j&1]
#pragma unroll
      for (int fn = 0; fn < 4; ++fn) {
        const bf16x8 bv =
            *(const bf16x8*)(wlds[j & 3] + g * 1024 + (fn * 16 + lrow) * 16);
#pragma unroll
        for (int fm = 0; fm < 4; ++fm)
          acc[fm][fn] = __builtin_amdgcn_mfma_f32_16x16x32_bf16(
              a2[j & 1][fm], bv, acc[fm][fn], 0, 0, 0);
      }
    }
  }

  // Epilogue: C/D layout col = lane&15, row = (lane>>4)*4 + q
#pragma unroll
  for (int fm = 0; fm < 4; ++fm)
#pragma unroll
    for (int q = 0; q < 4; ++q) {
      const int row = m0 + w * 64 + fm * 16 + g * 4 + q;
      float* po = out + (size_t)row * V_SZ + n0 + lrow;
#pragma unroll
      for (int fn = 0; fn < 4; ++fn) po[fn * 16] = acc[fm][fn][q];
    }
}

extern "C" void kernel_launch(void* const* d_in, const int* in_sizes, int n_in,
                              void* d_out, int out_size, void* d_ws, size_t ws_size,
                              hipStream_t stream) {
  const int* tokens = (const int*)d_in[0];
  const float* emb_ctx = (const float*)d_in[1];
  const float* emb_act = (const float*)d_in[2];
  const float* W = (const float*)d_in[3];
  const float* beta_mult = (const float*)d_in[4];
  const float* beta_power = (const float*)d_in[5];
  float* out = (float*)d_out;

  char* Mblk = (char*)d_ws;  // 4 MB, blocked layout
  float* ctx_hist = (float*)((char*)d_ws + (size_t)M_ROWS * K_DIM * 2);  // 128 KB

  ctx_kernel<<<B_SZ, C_DIM, 0, stream>>>(tokens, emb_ctx, beta_mult, beta_power,
                                         ctx_hist);
  build_m<<<M_ROWS, 128, 0, stream>>>(tokens, emb_act, ctx_hist, Mblk);
  gemm_kernel<<<NWG, 256, 0, stream>>>(Mblk, W, out);
}